// Round 12
// baseline (359.499 us; speedup 1.0000x reference)
//
#include <hip/hip_runtime.h>
#include <hip/hip_bf16.h>

typedef __attribute__((ext_vector_type(8))) short bf16x8;   // 8 bf16 in 4 VGPRs
typedef __attribute__((ext_vector_type(4))) float floatx4;
typedef __attribute__((ext_vector_type(16))) float floatx16;
typedef __attribute__((ext_vector_type(2))) int int2v;

#define MFMA_16x16x32(A, B, C) __builtin_amdgcn_mfma_f32_16x16x32_bf16(A, B, C, 0, 0, 0)
#define MFMA_32x32x16(A, B, C) __builtin_amdgcn_mfma_f32_32x32x16_bf16(A, B, C, 0, 0, 0)

__device__ __forceinline__ unsigned short f2b(float f) {
    __hip_bfloat16 h = __float2bfloat16(f);  // RNE
    unsigned short u;
    __builtin_memcpy(&u, &h, 2);
    return u;
}
// pack 2 floats -> 2 bf16 (RNE) in one u32 (v_cvt_pk_bf16_f32 on gfx950)
__device__ __forceinline__ unsigned pk2(float a, float b) {
    __hip_bfloat162 h = __float22bfloat162_rn(float2{a, b});
    unsigned u;
    __builtin_memcpy(&u, &h, 4);
    return u;
}
__device__ __forceinline__ bf16x8 mk8(int a, int b, int c, int d) {
    union { int u[4]; bf16x8 v; } x;
    x.u[0] = a; x.u[1] = b; x.u[2] = c; x.u[3] = d;
    return x.v;
}
__device__ __forceinline__ void async_lds16(const void* g, void* l) {
    __builtin_amdgcn_global_load_lds((__attribute__((address_space(1))) void*)g,
                                     (__attribute__((address_space(3))) void*)l, 16, 0, 0);
}

// ---------------- fp32 -> bf16 bulk convert (with per-tensor scale) ----------------
struct CvtArgs {
    const float* src[6];
    unsigned short* dst[6];
    float scale[6];
    int n8[6];
};
__global__ __launch_bounds__(256) void convert_kernel(CvtArgs a) {
    const int t = blockIdx.y;
    const int i = blockIdx.x * 256 + threadIdx.x;
    if (i >= a.n8[t]) return;
    const float sc = a.scale[t];
    const float4* s = (const float4*)a.src[t];
    const float4 x = s[2 * i], y = s[2 * i + 1];
    bf16x8 v;
    v[0] = (short)f2b(x.x * sc); v[1] = (short)f2b(x.y * sc);
    v[2] = (short)f2b(x.z * sc); v[3] = (short)f2b(x.w * sc);
    v[4] = (short)f2b(y.x * sc); v[5] = (short)f2b(y.y * sc);
    v[6] = (short)f2b(y.z * sc); v[7] = (short)f2b(y.w * sc);
    *(bf16x8*)(a.dst[t] + (size_t)i * 8) = v;
}

// ============ 256x256 4-phase GEMM, depth-1 staging (race-fixed from R11) ============
// BM=BN=256, BK=64, 8 waves, 512 thr, LDS 128KB, 1 block/CU. R11's race: staging
// tile t+2 during tile t hit the live read buffer (quadrant phases read BOTH halves
// every phase -> nothing frees early -> legal depth is 1 tile). Fix: stage tile t+1's
// 4 halves at phases 0-1 of tile t (buffer (t+1)&1, disjoint); vmcnt(0) moved to
// AFTER p==3's MFMA (last stage loads issued ~3 phases = ~900cyc earlier -> wait is
// typically pre-satisfied). Keeps: slot swizzle F(r)=(r&4)|((r&8)>>2) on both stage
// source and read side (involution), per-phase barriers + lgkmcnt(0)+sched_barrier,
// setprio(1) around MFMA clusters.
struct QKVArgs {
    const unsigned short* A[3];
    const unsigned short* B[3];
    const float* bias[3];
    float bscale[3];
    unsigned short* C[3];
};
__global__ __launch_bounds__(512, 2) void gemm_qkv(QKVArgs args) {
    constexpr int M = 8192, K = 1024;
    __shared__ __align__(16) unsigned short As[2][16384];   // [buf][row*64 + slot*8], 256 rows
    __shared__ __align__(16) unsigned short Bs[2][16384];

    const int z = blockIdx.z;
    const unsigned short* __restrict__ A = args.A[z];
    const unsigned short* __restrict__ B = args.B[z];
    const float* __restrict__ bias = args.bias[z];
    const float bsc = args.bscale[z];
    unsigned short* __restrict__ C = args.C[z];

    const int tid  = threadIdx.x;          // 0..511
    const int wave = tid >> 6;             // 0..7
    const int lane = tid & 63;
    const int l16  = lane & 15;
    const int quad = lane >> 4;
    const int bm = (blockIdx.x & 31) * 256;
    const int bn = (blockIdx.x >> 5) * 256;
    const int wm = (wave >> 2) * 128;      // 2 M-wave rows
    const int wn = (wave & 3) * 64;        // 4 N-wave cols

    const int srow  = tid >> 3;            // 0..63 staging row within 64-row chunk
    const int sslot = tid & 7;

    floatx4 acc[8][4] = {};

    auto stage_half = [&](int h) {         // h: half-tile; tile=h>>2, part=h&3
        const int tile = h >> 2;
        const int part = h & 3;            // 0:A-lo 1:A-hi 2:B-lo 3:B-hi
        const int k0   = tile * 64;
        const unsigned short* src = (part < 2) ? A : B;
        unsigned short* dst = (part < 2) ? &As[tile & 1][0] : &Bs[tile & 1][0];
        const int prow  = (part & 1) * 128;
        const int gbase = (part < 2) ? bm : bn;
        #pragma unroll
        for (int j = 0; j < 2; ++j) {
            const int r  = prow + j * 64 + srow;
            const int sc = sslot ^ ((r & 4) | ((r & 8) >> 2));
            async_lds16(src + (size_t)(gbase + r) * K + k0 + sc * 8,
                        dst + prow * 64 + j * 4096 + tid * 8);
        }
    };

    // prologue: tile 0 only (4 halves), full drain, barrier
    #pragma unroll
    for (int h = 0; h < 4; ++h) stage_half(h);
    asm volatile("s_waitcnt vmcnt(0)" ::: "memory");
    __builtin_amdgcn_s_barrier();
    __builtin_amdgcn_sched_barrier(0);

    for (int t = 0; t < 16; ++t) {
        const unsigned short* Ab = &As[t & 1][0];
        const unsigned short* Bb = &Bs[t & 1][0];
        #pragma unroll
        for (int p = 0; p < 4; ++p) {
            const int mh = p >> 1, nh = p & 1;
            bf16x8 af[4][2], bfr[2][2];
            #pragma unroll
            for (int i = 0; i < 4; ++i) {
                const int r  = wm + mh * 64 + i * 16 + l16;
                const int fr = (r & 4) | ((r & 8) >> 2);
                #pragma unroll
                for (int ks = 0; ks < 2; ++ks)
                    af[i][ks] = *(const bf16x8*)&Ab[r * 64 + ((ks * 4 + quad) ^ fr) * 8];
            }
            #pragma unroll
            for (int n = 0; n < 2; ++n) {
                const int r  = wn + nh * 32 + n * 16 + l16;
                const int fr = (r & 4) | ((r & 8) >> 2);
                #pragma unroll
                for (int ks = 0; ks < 2; ++ks)
                    bfr[n][ks] = *(const bf16x8*)&Bb[r * 64 + ((ks * 4 + quad) ^ fr) * 8];
            }
            // depth-1 staging: tile t+1's 4 halves, 2 at phase 0 and 2 at phase 1
            if (t < 15 && p < 2) {
                stage_half(4 * (t + 1) + 2 * p);
                stage_half(4 * (t + 1) + 2 * p + 1);
            }
            __builtin_amdgcn_s_barrier();
            asm volatile("s_waitcnt lgkmcnt(0)" ::: "memory");
            __builtin_amdgcn_sched_barrier(0);
            __builtin_amdgcn_s_setprio(1);
            #pragma unroll
            for (int ks = 0; ks < 2; ++ks)
                #pragma unroll
                for (int i = 0; i < 4; ++i)
                    #pragma unroll
                    for (int n = 0; n < 2; ++n)
                        acc[mh * 4 + i][nh * 2 + n] =
                            MFMA_16x16x32(af[i][ks], bfr[n][ks], acc[mh * 4 + i][nh * 2 + n]);
            __builtin_amdgcn_s_setprio(0);
            // late drain: last stage loads were issued ~3 phases ago -> usually free
            if (p == 3 && t < 15) asm volatile("s_waitcnt vmcnt(0)" ::: "memory");
            __builtin_amdgcn_s_barrier();
            __builtin_amdgcn_sched_barrier(0);
        }
    }

    if (z == 2) {
        // direct C^T b64 stores: C^T[col][row], lane's 4 acc values = consecutive rows
        #pragma unroll
        for (int nj = 0; nj < 4; ++nj) {
            const int col = bn + wn + (nj >> 1) * 32 + (nj & 1) * 16 + l16;
            const float bv = bias[col] * bsc;
            #pragma unroll
            for (int mi = 0; mi < 8; ++mi) {
                uint2 w;
                w.x = pk2(acc[mi][nj][0] + bv, acc[mi][nj][1] + bv);
                w.y = pk2(acc[mi][nj][2] + bv, acc[mi][nj][3] + bv);
                const size_t off = (size_t)col * (size_t)M
                                 + (bm + wm + (mi >> 2) * 64 + (mi & 3) * 16 + quad * 4);
                *(uint2*)&C[off] = w;
            }
        }
    } else {
        constexpr int N = 1024;
        #pragma unroll
        for (int mi = 0; mi < 8; ++mi) {
            const int row = bm + wm + (mi >> 2) * 64 + (mi & 3) * 16 + quad * 4;
            #pragma unroll
            for (int nj = 0; nj < 4; ++nj) {
                const int col = bn + wn + (nj >> 1) * 32 + (nj & 1) * 16 + l16;
                const float bv = bias[col] * bsc;
                #pragma unroll
                for (int r = 0; r < 4; ++r)
                    C[(size_t)(row + r) * N + col] = f2b(acc[mi][nj][r] + bv);
            }
        }
    }
}

// ---------------- output projection GEMM: same fixed 256x256 template, fp32 out ----------
__global__ __launch_bounds__(512, 2) void gemm_out(
    const unsigned short* __restrict__ A, const unsigned short* __restrict__ B,
    const float* __restrict__ bias, float* __restrict__ C,
    int M, int N, int K)
{
    __shared__ __align__(16) unsigned short As[2][16384];
    __shared__ __align__(16) unsigned short Bs[2][16384];

    const int tid  = threadIdx.x;
    const int wave = tid >> 6;
    const int lane = tid & 63;
    const int l16  = lane & 15;
    const int quad = lane >> 4;
    const int bm = (blockIdx.x & 31) * 256;
    const int bn = (blockIdx.x >> 5) * 256;
    const int wm = (wave >> 2) * 128;
    const int wn = (wave & 3) * 64;

    const int srow  = tid >> 3;
    const int sslot = tid & 7;

    floatx4 acc[8][4] = {};

    auto stage_half = [&](int h) {
        const int tile = h >> 2;
        const int part = h & 3;
        const int k0   = tile * 64;
        const unsigned short* src = (part < 2) ? A : B;
        unsigned short* dst = (part < 2) ? &As[tile & 1][0] : &Bs[tile & 1][0];
        const int prow  = (part & 1) * 128;
        const int gbase = (part < 2) ? bm : bn;
        #pragma unroll
        for (int j = 0; j < 2; ++j) {
            const int r  = prow + j * 64 + srow;
            const int sc = sslot ^ ((r & 4) | ((r & 8) >> 2));
            async_lds16(src + (size_t)(gbase + r) * K + k0 + sc * 8,
                        dst + prow * 64 + j * 4096 + tid * 8);
        }
    };

    #pragma unroll
    for (int h = 0; h < 4; ++h) stage_half(h);
    asm volatile("s_waitcnt vmcnt(0)" ::: "memory");
    __builtin_amdgcn_s_barrier();
    __builtin_amdgcn_sched_barrier(0);

    for (int t = 0; t < 16; ++t) {
        const unsigned short* Ab = &As[t & 1][0];
        const unsigned short* Bb = &Bs[t & 1][0];
        #pragma unroll
        for (int p = 0; p < 4; ++p) {
            const int mh = p >> 1, nh = p & 1;
            bf16x8 af[4][2], bfr[2][2];
            #pragma unroll
            for (int i = 0; i < 4; ++i) {
                const int r  = wm + mh * 64 + i * 16 + l16;
                const int fr = (r & 4) | ((r & 8) >> 2);
                #pragma unroll
                for (int ks = 0; ks < 2; ++ks)
                    af[i][ks] = *(const bf16x8*)&Ab[r * 64 + ((ks * 4 + quad) ^ fr) * 8];
            }
            #pragma unroll
            for (int n = 0; n < 2; ++n) {
                const int r  = wn + nh * 32 + n * 16 + l16;
                const int fr = (r & 4) | ((r & 8) >> 2);
                #pragma unroll
                for (int ks = 0; ks < 2; ++ks)
                    bfr[n][ks] = *(const bf16x8*)&Bb[r * 64 + ((ks * 4 + quad) ^ fr) * 8];
            }
            if (t < 15 && p < 2) {
                stage_half(4 * (t + 1) + 2 * p);
                stage_half(4 * (t + 1) + 2 * p + 1);
            }
            __builtin_amdgcn_s_barrier();
            asm volatile("s_waitcnt lgkmcnt(0)" ::: "memory");
            __builtin_amdgcn_sched_barrier(0);
            __builtin_amdgcn_s_setprio(1);
            #pragma unroll
            for (int ks = 0; ks < 2; ++ks)
                #pragma unroll
                for (int i = 0; i < 4; ++i)
                    #pragma unroll
                    for (int n = 0; n < 2; ++n)
                        acc[mh * 4 + i][nh * 2 + n] =
                            MFMA_16x16x32(af[i][ks], bfr[n][ks], acc[mh * 4 + i][nh * 2 + n]);
            __builtin_amdgcn_s_setprio(0);
            if (p == 3 && t < 15) asm volatile("s_waitcnt vmcnt(0)" ::: "memory");
            __builtin_amdgcn_s_barrier();
            __builtin_amdgcn_sched_barrier(0);
        }
    }

    #pragma unroll
    for (int mi = 0; mi < 8; ++mi) {
        const int row = bm + wm + (mi >> 2) * 64 + (mi & 3) * 16 + quad * 4;
        #pragma unroll
        for (int nj = 0; nj < 4; ++nj) {
            const int col = bn + wn + (nj >> 1) * 32 + (nj & 1) * 16 + l16;
            const float bv = bias[col];
            #pragma unroll
            for (int r = 0; r < 4; ++r)
                C[(size_t)(row + r) * N + col] = acc[mi][nj][r] + bv;
        }
    }
}

// ---------------- flash attention v12 (best, R9): 64 q-rows/wave ----------------
__global__ __launch_bounds__(256, 2) void attn_kernel(
    const unsigned short* __restrict__ Q, const unsigned short* __restrict__ Kg,
    const unsigned short* __restrict__ Vt, unsigned short* __restrict__ Y)
{
    __shared__ __align__(16) unsigned short Ks[2][4096];   // swizzled [kv(64)][d(64)]
    __shared__ __align__(16) unsigned short Vs[2][4096];   // swizzled [d(64)][kv(64)]

    const int tid  = threadIdx.x;
    const int wave = tid >> 6;      // 0..3
    const int lane = tid & 63;
    const int l31  = lane & 31;
    const int hi   = lane >> 5;     // 0/1
    const int x7   = lane & 7;
    const int h4   = ((lane >> 4) & 1) << 2;
    const int bh = blockIdx.x & 63;
    const int qt = blockIdx.x >> 6;          // 0..7
    const int b  = bh >> 4;
    const int h  = bh & 15;
    const int q0 = qt * 256 + wave * 64;     // wave owns q0..q0+63 (2 q-blocks of 32)
    const size_t base  = ((size_t)b * 2048) * 1024 + (size_t)h * 64;
    const size_t vbase = ((size_t)h * 64) * 8192 + (size_t)b * 2048;

    bf16x8 qf[2][4];
    #pragma unroll
    for (int qb = 0; qb < 2; ++qb) {
        const size_t qrow = base + (size_t)(q0 + qb * 32 + l31) * 1024 + hi * 8;
        #pragma unroll
        for (int ks = 0; ks < 4; ++ks)
            qf[qb][ks] = *(const bf16x8*)&Q[qrow + ks * 16];
    }

    bf16x8 ones;
    #pragma unroll
    for (int e = 0; e < 8; ++e) ones[e] = (short)0x3F80;   // bf16 1.0
    const floatx16 Z16 = {0.f,0.f,0.f,0.f,0.f,0.f,0.f,0.f,
                          0.f,0.f,0.f,0.f,0.f,0.f,0.f,0.f};

    floatx16 o[2][2] = {{Z16, Z16}, {Z16, Z16}};   // [qb][d-block]
    floatx16 rs[2]   = {Z16, Z16};                 // [qb] rowsum via ones-MFMA

    const int r0  = tid >> 3;
    const int csw = (tid & 7) ^ (r0 & 7) ^ (((tid >> 7) & 1) << 2);

    int co[4];
    #pragma unroll
    for (int ks = 0; ks < 4; ++ks) co[ks] = (((ks * 2 + hi) ^ x7 ^ h4) * 8);
    const int krow = l31 * 64;

    auto stage = [&](int buf, int kv0) {
        async_lds16(&Kg[base + (size_t)(kv0 + r0) * 1024 + csw * 8],      &Ks[buf][tid * 8]);
        async_lds16(&Kg[base + (size_t)(kv0 + 32 + r0) * 1024 + csw * 8], &Ks[buf][2048 + tid * 8]);
        async_lds16(&Vt[vbase + (size_t)r0 * 8192 + kv0 + csw * 8],        &Vs[buf][tid * 8]);
        async_lds16(&Vt[vbase + (size_t)(r0 + 32) * 8192 + kv0 + csw * 8], &Vs[buf][2048 + tid * 8]);
    };

    auto procP = [&](const floatx16& st, bf16x8& paA, bf16x8& paB) {
        float e[16];
        #pragma unroll
        for (int i = 0; i < 16; ++i) e[i] = __builtin_amdgcn_exp2f(st[i]);
        const int w0 = (int)pk2(e[0],  e[1]);
        const int w1 = (int)pk2(e[2],  e[3]);
        const int w2 = (int)pk2(e[4],  e[5]);
        const int w3 = (int)pk2(e[6],  e[7]);
        const int w4 = (int)pk2(e[8],  e[9]);
        const int w5 = (int)pk2(e[10], e[11]);
        const int w6 = (int)pk2(e[12], e[13]);
        const int w7 = (int)pk2(e[14], e[15]);
        const int2v a0 = __builtin_amdgcn_permlane32_swap(w0, w2, false, false);
        const int2v a1 = __builtin_amdgcn_permlane32_swap(w1, w3, false, false);
        const int2v a2 = __builtin_amdgcn_permlane32_swap(w4, w6, false, false);
        const int2v a3 = __builtin_amdgcn_permlane32_swap(w5, w7, false, false);
        paA = mk8(a0.x, a1.x, a0.y, a1.y);
        paB = mk8(a2.x, a3.x, a2.y, a3.y);
    };

    stage(0, 0);
    for (int t = 0; t < 32; ++t) {
        __syncthreads();
        if (t < 31) stage((t + 1) & 1, (t + 1) * 64);
        const unsigned short* Kc = &Ks[t & 1][0];
        const unsigned short* Vc = &Vs[t & 1][0];

        floatx16 st[2][2] = {{Z16, Z16}, {Z16, Z16}};   // [kv-half][qb]
        __builtin_amdgcn_s_setprio(1);
        #pragma unroll
        for (int ks = 0; ks < 4; ++ks) {
            const bf16x8 kf0 = *(const bf16x8*)&Kc[krow + co[ks]];
            const bf16x8 kf1 = *(const bf16x8*)&Kc[2048 + krow + co[ks]];
            st[0][0] = MFMA_32x32x16(kf0, qf[0][ks], st[0][0]);
            st[0][1] = MFMA_32x32x16(kf0, qf[1][ks], st[0][1]);
            st[1][0] = MFMA_32x32x16(kf1, qf[0][ks], st[1][0]);
            st[1][1] = MFMA_32x32x16(kf1, qf[1][ks], st[1][1]);
        }
        __builtin_amdgcn_s_setprio(0);

        bf16x8 pa[4][2];
        procP(st[0][0], pa[0][0], pa[1][0]);
        procP(st[0][1], pa[0][1], pa[1][1]);
        procP(st[1][0], pa[2][0], pa[3][0]);
        procP(st[1][1], pa[2][1], pa[3][1]);

        __builtin_amdgcn_s_setprio(1);
        #pragma unroll
        for (int f = 0; f < 4; ++f) {
            const bf16x8 v0 = *(const bf16x8*)&Vc[krow + co[f]];
            const bf16x8 v1 = *(const bf16x8*)&Vc[2048 + krow + co[f]];
            #pragma unroll
            for (int qb = 0; qb < 2; ++qb) {
                o[qb][0] = MFMA_32x32x16(pa[f][qb], v0, o[qb][0]);
                o[qb][1] = MFMA_32x32x16(pa[f][qb], v1, o[qb][1]);
                rs[qb]   = MFMA_32x32x16(pa[f][qb], ones, rs[qb]);
            }
        }
        __builtin_amdgcn_s_setprio(0);
    }

    #pragma unroll
    for (int qb = 0; qb < 2; ++qb) {
        #pragma unroll
        for (int g = 0; g < 4; ++g) {
            #pragma unroll
            for (int e2 = 0; e2 < 4; ++e2) {
                const int reg = g * 4 + e2;
                const float inv = 1.0f / rs[qb][reg];
                const size_t row = q0 + qb * 32 + 8 * g + 4 * hi + e2;
                Y[base + row * 1024 + l31]      = f2b(o[qb][0][reg] * inv);
                Y[base + row * 1024 + 32 + l31] = f2b(o[qb][1][reg] * inv);
            }
        }
    }
}

extern "C" void kernel_launch(void* const* d_in, const int* in_sizes, int n_in,
                              void* d_out, int out_size, void* d_ws, size_t ws_size,
                              hipStream_t stream)
{
    const float* dec = (const float*)d_in[0];
    const float* enc = (const float*)d_in[1];
    const float* Wq  = (const float*)d_in[2];
    const float* bq  = (const float*)d_in[3];
    const float* Wk  = (const float*)d_in[4];
    const float* bk  = (const float*)d_in[5];
    const float* Wv  = (const float*)d_in[6];
    const float* bv  = (const float*)d_in[7];
    const float* Wp  = (const float*)d_in[8];
    const float* bp  = (const float*)d_in[9];

    const size_t NTOK = 8192, DM = 1024;
    unsigned short* ws = (unsigned short*)d_ws;
    unsigned short* decB = ws;
    unsigned short* encB = decB + NTOK * DM;
    unsigned short* WqB  = encB + NTOK * DM;
    unsigned short* WkB  = WqB + DM * DM;
    unsigned short* WvB  = WkB + DM * DM;
    unsigned short* WpB  = WvB + DM * DM;
    unsigned short* Qb   = WpB + DM * DM;
    unsigned short* Kb   = Qb + NTOK * DM;
    unsigned short* VtG  = Kb + NTOK * DM;           // [1024][8192]
    unsigned short* Yb   = VtG + NTOK * DM;

    const float C_SM = 0.18033688f;   // log2(e) / sqrt(64)

    CvtArgs a;
    a.src[0] = dec; a.src[1] = enc; a.src[2] = Wq; a.src[3] = Wk; a.src[4] = Wv; a.src[5] = Wp;
    a.dst[0] = decB; a.dst[1] = encB; a.dst[2] = WqB; a.dst[3] = WkB; a.dst[4] = WvB; a.dst[5] = WpB;
    a.scale[0] = 1.f; a.scale[1] = 1.f; a.scale[2] = C_SM;
    a.scale[3] = 1.f; a.scale[4] = 1.f; a.scale[5] = 1.f;
    a.n8[0] = a.n8[1] = (int)(NTOK * DM / 8);
    a.n8[2] = a.n8[3] = a.n8[4] = a.n8[5] = (int)(DM * DM / 8);
    convert_kernel<<<dim3(4096, 6), 256, 0, stream>>>(a);

    QKVArgs qa;
    qa.A[0] = decB; qa.A[1] = encB; qa.A[2] = encB;
    qa.B[0] = WqB;  qa.B[1] = WkB;  qa.B[2] = WvB;
    qa.bias[0] = bq; qa.bias[1] = bk; qa.bias[2] = bv;
    qa.bscale[0] = C_SM; qa.bscale[1] = 1.f; qa.bscale[2] = 1.f;
    qa.C[0] = Qb;   qa.C[1] = Kb;   qa.C[2] = VtG;
    gemm_qkv<<<dim3(128, 1, 3), 512, 0, stream>>>(qa);

    attn_kernel<<<dim3(512), 256, 0, stream>>>(Qb, Kb, VtG, Yb);
    gemm_out<<<dim3(128), 512, 0, stream>>>(Yb, WpB, bp, (float*)d_out, 8192, 1024, 1024);
}

// Round 13
// 307.255 us; speedup vs baseline: 1.1700x; 1.1700x over previous
//
#include <hip/hip_runtime.h>
#include <hip/hip_bf16.h>

typedef __attribute__((ext_vector_type(8))) short bf16x8;   // 8 bf16 in 4 VGPRs
typedef __attribute__((ext_vector_type(4))) float floatx4;
typedef __attribute__((ext_vector_type(16))) float floatx16;
typedef __attribute__((ext_vector_type(2))) int int2v;

#define MFMA_16x16x32(A, B, C) __builtin_amdgcn_mfma_f32_16x16x32_bf16(A, B, C, 0, 0, 0)
#define MFMA_32x32x16(A, B, C) __builtin_amdgcn_mfma_f32_32x32x16_bf16(A, B, C, 0, 0, 0)

__device__ __forceinline__ unsigned short f2b(float f) {
    __hip_bfloat16 h = __float2bfloat16(f);  // RNE
    unsigned short u;
    __builtin_memcpy(&u, &h, 2);
    return u;
}
// pack 2 floats -> 2 bf16 (RNE) in one u32 (v_cvt_pk_bf16_f32 on gfx950)
__device__ __forceinline__ unsigned pk2(float a, float b) {
    __hip_bfloat162 h = __float22bfloat162_rn(float2{a, b});
    unsigned u;
    __builtin_memcpy(&u, &h, 4);
    return u;
}
__device__ __forceinline__ bf16x8 mk8(int a, int b, int c, int d) {
    union { int u[4]; bf16x8 v; } x;
    x.u[0] = a; x.u[1] = b; x.u[2] = c; x.u[3] = d;
    return x.v;
}
__device__ __forceinline__ void async_lds16(const void* g, void* l) {
    __builtin_amdgcn_global_load_lds((__attribute__((address_space(1))) void*)g,
                                     (__attribute__((address_space(3))) void*)l, 16, 0, 0);
}

// ---------------- fp32 -> bf16 bulk convert (with per-tensor scale) ----------------
struct CvtArgs {
    const float* src[6];
    unsigned short* dst[6];
    float scale[6];
    int n8[6];
};
__global__ __launch_bounds__(256) void convert_kernel(CvtArgs a) {
    const int t = blockIdx.y;
    const int i = blockIdx.x * 256 + threadIdx.x;
    if (i >= a.n8[t]) return;
    const float sc = a.scale[t];
    const float4* s = (const float4*)a.src[t];
    const float4 x = s[2 * i], y = s[2 * i + 1];
    bf16x8 v;
    v[0] = (short)f2b(x.x * sc); v[1] = (short)f2b(x.y * sc);
    v[2] = (short)f2b(x.z * sc); v[3] = (short)f2b(x.w * sc);
    v[4] = (short)f2b(y.x * sc); v[5] = (short)f2b(y.y * sc);
    v[6] = (short)f2b(y.z * sc); v[7] = (short)f2b(y.w * sc);
    *(bf16x8*)(a.dst[t] + (size_t)i * 8) = v;
}

// ---------------- fused QKV projection GEMM: 128x128, 4 waves, 4 blocks/CU (R5 config) ----
// Read swizzle F(r) = (r&3)^((r>>2)&3): even rows cover all 4 slots x2, odd rows
// shifted by 16 banks -> 2-way aliasing = free (verified vs R12's broken even-only F).
struct QKVArgs {
    const unsigned short* A[3];
    const unsigned short* B[3];
    const float* bias[3];
    float bscale[3];
    unsigned short* C[3];
};
__global__ __launch_bounds__(256, 4) void gemm_qkv(QKVArgs args) {
    constexpr int M = 8192, N = 1024, K = 1024;
    __shared__ __align__(16) unsigned short As[2][4096];   // 128 x 32
    __shared__ __align__(16) unsigned short Bs[2][4096];   // 128 x 32

    const int z = blockIdx.z;
    const unsigned short* __restrict__ A = args.A[z];
    const unsigned short* __restrict__ B = args.B[z];
    const float* __restrict__ bias = args.bias[z];
    const float bsc = args.bscale[z];
    unsigned short* __restrict__ C = args.C[z];

    const int tid  = threadIdx.x;
    const int wave = tid >> 6;      // 0..3
    const int lane = tid & 63;
    const int l16  = lane & 15;
    const int quad = lane >> 4;
    const int bm = (blockIdx.x & 63) * 128;
    const int bn = (blockIdx.x >> 6) * 128;
    const int wm = (wave >> 1) * 64;
    const int wn = (wave & 1) * 64;

    const int srow = tid >> 2;                                                // 0..63
    const int skb  = (((tid & 3) ^ ((tid >> 2) & 3) ^ ((tid >> 4) & 3)) * 8); // chunk ^ F(row)
    const int cq   = ((quad ^ (l16 & 3) ^ ((l16 >> 2) & 3)) * 8);             // read: quad ^ F(row)

    floatx4 acc[4][4] = {};

    auto stage = [&](int buf, int k0) {
        async_lds16(A + (size_t)(bm + srow) * K + skb + k0,      &As[buf][tid * 8]);
        async_lds16(A + (size_t)(bm + 64 + srow) * K + skb + k0, &As[buf][2048 + tid * 8]);
        async_lds16(B + (size_t)(bn + srow) * K + skb + k0,      &Bs[buf][tid * 8]);
        async_lds16(B + (size_t)(bn + 64 + srow) * K + skb + k0, &Bs[buf][2048 + tid * 8]);
    };

    stage(0, 0);
    for (int it = 0; it < K / 32; ++it) {
        __syncthreads();
        if (it + 1 < K / 32) stage((it + 1) & 1, (it + 1) * 32);
        const unsigned short* Ac = &As[it & 1][0];
        const unsigned short* Bc = &Bs[it & 1][0];

        bf16x8 af[4], bfr[4];
        #pragma unroll
        for (int i = 0; i < 4; ++i)
            af[i] = *(const bf16x8*)&Ac[(wm + i * 16 + l16) * 32 + cq];
        #pragma unroll
        for (int j = 0; j < 4; ++j)
            bfr[j] = *(const bf16x8*)&Bc[(wn + j * 16 + l16) * 32 + cq];
        #pragma unroll
        for (int i = 0; i < 4; ++i)
            #pragma unroll
            for (int j = 0; j < 4; ++j)
                acc[i][j] = MFMA_16x16x32(af[i], bfr[j], acc[i][j]);
    }

    if (z == 2) {
        // direct C^T b64 stores: C^T[col][row], lane's 4 acc values are consecutive rows
        #pragma unroll
        for (int j = 0; j < 4; ++j) {
            const int col = bn + wn + j * 16 + l16;
            const float bv = bias[col] * bsc;
            #pragma unroll
            for (int i = 0; i < 4; ++i) {
                uint2 w;
                w.x = pk2(acc[i][j][0] + bv, acc[i][j][1] + bv);
                w.y = pk2(acc[i][j][2] + bv, acc[i][j][3] + bv);
                const size_t off = (size_t)col * (size_t)M + (bm + wm + i * 16 + quad * 4);
                *(uint2*)&C[off] = w;
            }
        }
    } else {
        #pragma unroll
        for (int i = 0; i < 4; ++i) {
            const int row = bm + wm + i * 16 + quad * 4;
            #pragma unroll
            for (int j = 0; j < 4; ++j) {
                const int col = bn + wn + j * 16 + l16;
                const float bv = bias[col] * bsc;
                #pragma unroll
                for (int r = 0; r < 4; ++r)
                    C[(size_t)(row + r) * N + col] = f2b(acc[i][j][r] + bv);
            }
        }
    }
}

// ---------------- output projection GEMM: 128x128, 4 waves + coalesced LDS epilogue --------
__global__ __launch_bounds__(256, 4) void gemm_out(
    const unsigned short* __restrict__ A, const unsigned short* __restrict__ B,
    const float* __restrict__ bias, float* __restrict__ C,
    int M, int N, int K)
{
    __shared__ __align__(16) unsigned short As[2][4096];
    __shared__ __align__(16) unsigned short Bs[2][4096];

    const int tid  = threadIdx.x;
    const int wave = tid >> 6;
    const int lane = tid & 63;
    const int l16  = lane & 15;
    const int quad = lane >> 4;
    const int bm = (blockIdx.x & 63) * 128;
    const int bn = (blockIdx.x >> 6) * 128;
    const int wm = (wave >> 1) * 64;
    const int wn = (wave & 1) * 64;

    const int srow = tid >> 2;
    const int skb  = (((tid & 3) ^ ((tid >> 2) & 3) ^ ((tid >> 4) & 3)) * 8);
    const int cq   = ((quad ^ (l16 & 3) ^ ((l16 >> 2) & 3)) * 8);

    floatx4 acc[4][4] = {};

    auto stage = [&](int buf, int k0) {
        async_lds16(A + (size_t)(bm + srow) * K + skb + k0,      &As[buf][tid * 8]);
        async_lds16(A + (size_t)(bm + 64 + srow) * K + skb + k0, &As[buf][2048 + tid * 8]);
        async_lds16(B + (size_t)(bn + srow) * K + skb + k0,      &Bs[buf][tid * 8]);
        async_lds16(B + (size_t)(bn + 64 + srow) * K + skb + k0, &Bs[buf][2048 + tid * 8]);
    };

    stage(0, 0);
    for (int it = 0; it < K / 32; ++it) {
        __syncthreads();
        if (it + 1 < K / 32) stage((it + 1) & 1, (it + 1) * 32);
        const unsigned short* Ac = &As[it & 1][0];
        const unsigned short* Bc = &Bs[it & 1][0];

        bf16x8 af[4], bfr[4];
        #pragma unroll
        for (int i = 0; i < 4; ++i)
            af[i] = *(const bf16x8*)&Ac[(wm + i * 16 + l16) * 32 + cq];
        #pragma unroll
        for (int j = 0; j < 4; ++j)
            bfr[j] = *(const bf16x8*)&Bc[(wn + j * 16 + l16) * 32 + cq];
        #pragma unroll
        for (int i = 0; i < 4; ++i)
            #pragma unroll
            for (int j = 0; j < 4; ++j)
                acc[i][j] = MFMA_16x16x32(af[i], bfr[j], acc[i][j]);
    }

    // ---- barrier-free coalesced epilogue (As[0]/Bs[0] dead after K-loop) ----
    float* Tw = ((wave < 2) ? (float*)&As[0][0] : (float*)&Bs[0][0]) + (wave & 1) * 1024;
    const int rrow = lane >> 2;          // 0..15: local output row
    const int rch  = lane & 3;           // 16B col-chunk base
    #pragma unroll
    for (int i = 0; i < 4; ++i) {
        #pragma unroll
        for (int j = 0; j < 4; ++j) {
            const int col = j * 16 + l16;
            const float bv = bias[bn + wn + col];
            floatx4 v;
            #pragma unroll
            for (int r = 0; r < 4; ++r) v[r] = acc[i][j][r] + bv;
            *(floatx4*)&Tw[col * 16 + ((quad ^ (col & 3)) << 2)] = v;
        }
        const int grow = bm + wm + i * 16 + rrow;
        #pragma unroll
        for (int k = 0; k < 4; ++k) {
            const int c0 = (rch + 4 * k) * 4;
            floatx4 v;
            #pragma unroll
            for (int c = 0; c < 4; ++c) {
                const int col = c0 + c;
                v[c] = Tw[col * 16 + ((((rrow >> 2) ^ col) & 3) << 2) + (rrow & 3)];
            }
            *(floatx4*)&C[(size_t)grow * N + bn + wn + c0] = v;
        }
    }
}

// ---------------- flash attention v12 (best, R9): 64 q-rows/wave ----------------
__global__ __launch_bounds__(256, 2) void attn_kernel(
    const unsigned short* __restrict__ Q, const unsigned short* __restrict__ Kg,
    const unsigned short* __restrict__ Vt, unsigned short* __restrict__ Y)
{
    __shared__ __align__(16) unsigned short Ks[2][4096];   // swizzled [kv(64)][d(64)]
    __shared__ __align__(16) unsigned short Vs[2][4096];   // swizzled [d(64)][kv(64)]

    const int tid  = threadIdx.x;
    const int wave = tid >> 6;      // 0..3
    const int lane = tid & 63;
    const int l31  = lane & 31;
    const int hi   = lane >> 5;     // 0/1
    const int x7   = lane & 7;
    const int h4   = ((lane >> 4) & 1) << 2;
    const int bh = blockIdx.x & 63;
    const int qt = blockIdx.x >> 6;          // 0..7
    const int b  = bh >> 4;
    const int h  = bh & 15;
    const int q0 = qt * 256 + wave * 64;     // wave owns q0..q0+63 (2 q-blocks of 32)
    const size_t base  = ((size_t)b * 2048) * 1024 + (size_t)h * 64;
    const size_t vbase = ((size_t)h * 64) * 8192 + (size_t)b * 2048;

    bf16x8 qf[2][4];
    #pragma unroll
    for (int qb = 0; qb < 2; ++qb) {
        const size_t qrow = base + (size_t)(q0 + qb * 32 + l31) * 1024 + hi * 8;
        #pragma unroll
        for (int ks = 0; ks < 4; ++ks)
            qf[qb][ks] = *(const bf16x8*)&Q[qrow + ks * 16];
    }

    bf16x8 ones;
    #pragma unroll
    for (int e = 0; e < 8; ++e) ones[e] = (short)0x3F80;   // bf16 1.0
    const floatx16 Z16 = {0.f,0.f,0.f,0.f,0.f,0.f,0.f,0.f,
                          0.f,0.f,0.f,0.f,0.f,0.f,0.f,0.f};

    floatx16 o[2][2] = {{Z16, Z16}, {Z16, Z16}};   // [qb][d-block]
    floatx16 rs[2]   = {Z16, Z16};                 // [qb] rowsum via ones-MFMA

    const int r0  = tid >> 3;
    const int csw = (tid & 7) ^ (r0 & 7) ^ (((tid >> 7) & 1) << 2);

    int co[4];
    #pragma unroll
    for (int ks = 0; ks < 4; ++ks) co[ks] = (((ks * 2 + hi) ^ x7 ^ h4) * 8);
    const int krow = l31 * 64;

    auto stage = [&](int buf, int kv0) {
        async_lds16(&Kg[base + (size_t)(kv0 + r0) * 1024 + csw * 8],      &Ks[buf][tid * 8]);
        async_lds16(&Kg[base + (size_t)(kv0 + 32 + r0) * 1024 + csw * 8], &Ks[buf][2048 + tid * 8]);
        async_lds16(&Vt[vbase + (size_t)r0 * 8192 + kv0 + csw * 8],        &Vs[buf][tid * 8]);
        async_lds16(&Vt[vbase + (size_t)(r0 + 32) * 8192 + kv0 + csw * 8], &Vs[buf][2048 + tid * 8]);
    };

    auto procP = [&](const floatx16& st, bf16x8& paA, bf16x8& paB) {
        float e[16];
        #pragma unroll
        for (int i = 0; i < 16; ++i) e[i] = __builtin_amdgcn_exp2f(st[i]);
        const int w0 = (int)pk2(e[0],  e[1]);
        const int w1 = (int)pk2(e[2],  e[3]);
        const int w2 = (int)pk2(e[4],  e[5]);
        const int w3 = (int)pk2(e[6],  e[7]);
        const int w4 = (int)pk2(e[8],  e[9]);
        const int w5 = (int)pk2(e[10], e[11]);
        const int w6 = (int)pk2(e[12], e[13]);
        const int w7 = (int)pk2(e[14], e[15]);
        const int2v a0 = __builtin_amdgcn_permlane32_swap(w0, w2, false, false);
        const int2v a1 = __builtin_amdgcn_permlane32_swap(w1, w3, false, false);
        const int2v a2 = __builtin_amdgcn_permlane32_swap(w4, w6, false, false);
        const int2v a3 = __builtin_amdgcn_permlane32_swap(w5, w7, false, false);
        paA = mk8(a0.x, a1.x, a0.y, a1.y);
        paB = mk8(a2.x, a3.x, a2.y, a3.y);
    };

    stage(0, 0);
    for (int t = 0; t < 32; ++t) {
        __syncthreads();
        if (t < 31) stage((t + 1) & 1, (t + 1) * 64);
        const unsigned short* Kc = &Ks[t & 1][0];
        const unsigned short* Vc = &Vs[t & 1][0];

        floatx16 st[2][2] = {{Z16, Z16}, {Z16, Z16}};   // [kv-half][qb]
        __builtin_amdgcn_s_setprio(1);
        #pragma unroll
        for (int ks = 0; ks < 4; ++ks) {
            const bf16x8 kf0 = *(const bf16x8*)&Kc[krow + co[ks]];
            const bf16x8 kf1 = *(const bf16x8*)&Kc[2048 + krow + co[ks]];
            st[0][0] = MFMA_32x32x16(kf0, qf[0][ks], st[0][0]);
            st[0][1] = MFMA_32x32x16(kf0, qf[1][ks], st[0][1]);
            st[1][0] = MFMA_32x32x16(kf1, qf[0][ks], st[1][0]);
            st[1][1] = MFMA_32x32x16(kf1, qf[1][ks], st[1][1]);
        }
        __builtin_amdgcn_s_setprio(0);

        bf16x8 pa[4][2];
        procP(st[0][0], pa[0][0], pa[1][0]);
        procP(st[0][1], pa[0][1], pa[1][1]);
        procP(st[1][0], pa[2][0], pa[3][0]);
        procP(st[1][1], pa[2][1], pa[3][1]);

        __builtin_amdgcn_s_setprio(1);
        #pragma unroll
        for (int f = 0; f < 4; ++f) {
            const bf16x8 v0 = *(const bf16x8*)&Vc[krow + co[f]];
            const bf16x8 v1 = *(const bf16x8*)&Vc[2048 + krow + co[f]];
            #pragma unroll
            for (int qb = 0; qb < 2; ++qb) {
                o[qb][0] = MFMA_32x32x16(pa[f][qb], v0, o[qb][0]);
                o[qb][1] = MFMA_32x32x16(pa[f][qb], v1, o[qb][1]);
                rs[qb]   = MFMA_32x32x16(pa[f][qb], ones, rs[qb]);
            }
        }
        __builtin_amdgcn_s_setprio(0);
    }

    #pragma unroll
    for (int qb = 0; qb < 2; ++qb) {
        #pragma unroll
        for (int g = 0; g < 4; ++g) {
            #pragma unroll
            for (int e2 = 0; e2 < 4; ++e2) {
                const int reg = g * 4 + e2;
                const float inv = 1.0f / rs[qb][reg];
                const size_t row = q0 + qb * 32 + 8 * g + 4 * hi + e2;
                Y[base + row * 1024 + l31]      = f2b(o[qb][0][reg] * inv);
                Y[base + row * 1024 + 32 + l31] = f2b(o[qb][1][reg] * inv);
            }
        }
    }
}

extern "C" void kernel_launch(void* const* d_in, const int* in_sizes, int n_in,
                              void* d_out, int out_size, void* d_ws, size_t ws_size,
                              hipStream_t stream)
{
    const float* dec = (const float*)d_in[0];
    const float* enc = (const float*)d_in[1];
    const float* Wq  = (const float*)d_in[2];
    const float* bq  = (const float*)d_in[3];
    const float* Wk  = (const float*)d_in[4];
    const float* bk  = (const float*)d_in[5];
    const float* Wv  = (const float*)d_in[6];
    const float* bv  = (const float*)d_in[7];
    const float* Wp  = (const float*)d_in[8];
    const float* bp  = (const float*)d_in[9];

    const size_t NTOK = 8192, DM = 1024;
    unsigned short* ws = (unsigned short*)d_ws;
    unsigned short* decB = ws;
    unsigned short* encB = decB + NTOK * DM;
    unsigned short* WqB  = encB + NTOK * DM;
    unsigned short* WkB  = WqB + DM * DM;
    unsigned short* WvB  = WkB + DM * DM;
    unsigned short* WpB  = WvB + DM * DM;
    unsigned short* Qb   = WpB + DM * DM;
    unsigned short* Kb   = Qb + NTOK * DM;
    unsigned short* VtG  = Kb + NTOK * DM;           // [1024][8192]
    unsigned short* Yb   = VtG + NTOK * DM;

    const float C_SM = 0.18033688f;   // log2(e) / sqrt(64)

    CvtArgs a;
    a.src[0] = dec; a.src[1] = enc; a.src[2] = Wq; a.src[3] = Wk; a.src[4] = Wv; a.src[5] = Wp;
    a.dst[0] = decB; a.dst[1] = encB; a.dst[2] = WqB; a.dst[3] = WkB; a.dst[4] = WvB; a.dst[5] = WpB;
    a.scale[0] = 1.f; a.scale[1] = 1.f; a.scale[2] = C_SM;
    a.scale[3] = 1.f; a.scale[4] = 1.f; a.scale[5] = 1.f;
    a.n8[0] = a.n8[1] = (int)(NTOK * DM / 8);
    a.n8[2] = a.n8[3] = a.n8[4] = a.n8[5] = (int)(DM * DM / 8);
    convert_kernel<<<dim3(4096, 6), 256, 0, stream>>>(a);

    QKVArgs qa;
    qa.A[0] = decB; qa.A[1] = encB; qa.A[2] = encB;
    qa.B[0] = WqB;  qa.B[1] = WkB;  qa.B[2] = WvB;
    qa.bias[0] = bq; qa.bias[1] = bk; qa.bias[2] = bv;
    qa.bscale[0] = C_SM; qa.bscale[1] = 1.f; qa.bscale[2] = 1.f;
    qa.C[0] = Qb;   qa.C[1] = Kb;   qa.C[2] = VtG;
    gemm_qkv<<<dim3(512, 1, 3), 256, 0, stream>>>(qa);

    attn_kernel<<<dim3(512), 256, 0, stream>>>(Qb, Kb, VtG, Yb);
    gemm_out<<<dim3(512), 256, 0, stream>>>(Yb, WpB, bp, (float*)d_out, 8192, 1024, 1024);
}